// Round 4
// 346.522 us; speedup vs baseline: 1.0512x; 1.0512x over previous
//
#include <hip/hip_runtime.h>

typedef __attribute__((ext_vector_type(8))) short bf16x8;
typedef __attribute__((ext_vector_type(4))) float f32x4;

#define NEG_SLOPE 0.2f

__device__ __forceinline__ unsigned short f2bf(float f){
  unsigned u = __float_as_uint(f);
  u = (u + 0x7fffu + ((u >> 16) & 1u)) >> 16;   // RNE
  return (unsigned short)u;
}
__device__ __forceinline__ float bflo(unsigned u){ return __uint_as_float(u << 16); }
__device__ __forceinline__ float bfhi(unsigned u){ return __uint_as_float(u & 0xffff0000u); }
__device__ __forceinline__ float lrelu(float x){ return x > 0.f ? x : NEG_SLOPE * x; }

// ---------------------------------------------------------------------------
// K1: fused [hist | type-hist | bprep].  (unchanged, verified)
// ---------------------------------------------------------------------------
__global__ __launch_bounds__(256) void k_histprep(
    const int* __restrict__ edges, const int* __restrict__ vertex, int NNZ,
    int* __restrict__ cnt, int E, int nbHist,
    const int* __restrict__ vtype, int N, int* __restrict__ tcnt, int nbHN,
    const float* __restrict__ W, short* __restrict__ Bfrag){
  __shared__ int lcnt[4];
  int b = (int)blockIdx.x;
  if (b < nbHist){
    int i = b * 256 + threadIdx.x;
    if (i < NNZ){
      atomicAdd(cnt + edges[i], 1);
      atomicAdd(cnt + E + vertex[i], 1);
    }
    return;
  }
  b -= nbHist;
  if (b < nbHN){
    if (threadIdx.x < 4) lcnt[threadIdx.x] = 0;
    __syncthreads();
    int i = b * 256 + threadIdx.x;
    if (i < N) atomicAdd(&lcnt[vtype[i]], 1);
    __syncthreads();
    if (threadIdx.x < 4 && lcnt[threadIdx.x] > 0)
      atomicAdd(tcnt + threadIdx.x, lcnt[threadIdx.x]);
    return;
  }
  b -= nbHN;
  int u = b * 256 + threadIdx.x;                   // 0..65535
  int j = u & 7, lane = (u >> 3) & 63, ct = (u >> 9) & 31, ks = u >> 14;
  int k = ks * 32 + ((lane >> 4) << 3) + j;
  int col = (ct << 4) + (lane & 15);
  int t = col >> 7, o = col & 127;
  Bfrag[u] = (short)f2bf(W[(t * 128 + k) * 128 + o]);
}

// ---------------------------------------------------------------------------
// scans (unchanged, verified)
// ---------------------------------------------------------------------------
__global__ __launch_bounds__(256) void k_scanA(const int* __restrict__ cnt, int S,
                                               int* __restrict__ bsum){
  __shared__ int sh[256];
  int base = blockIdx.x * 1024 + threadIdx.x * 4;
  int s = 0;
  #pragma unroll
  for (int k = 0; k < 4; ++k){ int idx = base + k; if (idx < S) s += cnt[idx]; }
  sh[threadIdx.x] = s; __syncthreads();
  for (int off = 128; off > 0; off >>= 1){
    if (threadIdx.x < off) sh[threadIdx.x] += sh[threadIdx.x + off];
    __syncthreads();
  }
  if (threadIdx.x == 0) bsum[blockIdx.x] = sh[0];
}

__global__ void k_scanB(int* bsum, int nb, const int* __restrict__ tcnt,
                        int* __restrict__ pbase){
  if (threadIdx.x == 0 && blockIdx.x == 0){
    int run = 0;
    for (int b = 0; b < nb; ++b){ int v = bsum[b]; bsum[b] = run; run += v; }
    int pb = 0;
    for (int t = 0; t < 4; ++t){
      pbase[t] = pb;
      pb += ((tcnt[t] + 63) >> 6) << 6;            // pad to 64-row multiple
    }
    pbase[4] = pb;
  }
}

__global__ __launch_bounds__(256) void k_scanC(const int* __restrict__ cnt, int S,
    const int* __restrict__ bsum, int* __restrict__ offs, int* __restrict__ cursor,
    int nbS, const int* __restrict__ vtype, int N, const int* __restrict__ pbase,
    int* __restrict__ tcur, int* __restrict__ nsorted){
  __shared__ int sh[256];
  __shared__ int gbase[4];
  int t = threadIdx.x;
  int b = (int)blockIdx.x;
  if (b >= nbS){                                   // node-place role
    int* lcnt = sh;
    if (t < 4) lcnt[t] = 0;
    __syncthreads();
    int i = (b - nbS) * 256 + t;
    int tt = 0, rank = 0;
    bool valid = i < N;
    if (valid){ tt = vtype[i]; rank = atomicAdd(&lcnt[tt], 1); }
    __syncthreads();
    if (t < 4 && lcnt[t] > 0) gbase[t] = atomicAdd(tcur + t, lcnt[t]);
    __syncthreads();
    if (valid) nsorted[pbase[tt] + gbase[tt] + rank] = i;
    return;
  }
  int base = b * 1024 + t * 4;
  int c[4]; int s = 0;
  #pragma unroll
  for (int k = 0; k < 4; ++k){ int idx = base + k; c[k] = (idx < S) ? cnt[idx] : 0; s += c[k]; }
  sh[t] = s; __syncthreads();
  for (int off = 1; off < 256; off <<= 1){
    int v = (t >= off) ? sh[t - off] : 0; __syncthreads();
    sh[t] += v; __syncthreads();
  }
  int run = bsum[b] + sh[t] - s;                   // exclusive prefix for this thread
  #pragma unroll
  for (int k = 0; k < 4; ++k){
    int idx = base + k;
    if (idx < S){ offs[idx] = run; cursor[idx] = run; run += c[k]; }
  }
}

// ---------------------------------------------------------------------------
// F_A: fused [type-sorted gemm | place_e], MODULO-interleaved period 3.
// EXACT passing-kernel version.
// ---------------------------------------------------------------------------
__global__ __launch_bounds__(256, 3) void k_gemm_place(const float* __restrict__ X,
    const short* __restrict__ Bfrag, const int* __restrict__ nsorted,
    const int* __restrict__ pbase, unsigned short* __restrict__ X0,
    const int* __restrict__ edges, const int* __restrict__ vertex, int NNZ,
    int* __restrict__ cursor, int* __restrict__ rows, int nbPlace){
  __shared__ short shB[8 * 4 * 64 * 8];            // 32KB: type slab, frag order
  const int tid = threadIdx.x;
  const int q = (int)blockIdx.x / 3, r = (int)blockIdx.x % 3;

  if (r != 0){                                     // place_e role
    int hb = 2 * q + (r - 1);
    if (hb < nbPlace){
      int i = hb * 256 + tid;
      if (i < NNZ){
        int pos = atomicAdd(cursor + edges[i], 1);
        rows[pos] = vertex[i];
      }
    }
    return;
  }

  const int rowIdx = q * 64;
  const int t = (rowIdx >= pbase[1]) + (rowIdx >= pbase[2]) + (rowIdx >= pbase[3]);

  // stage this type's full B (8 ct x 4 ks x 64 lanes, bf16x8 units)
  const bf16x8* Bv = (const bf16x8*)Bfrag;
  bf16x8* shBv = (bf16x8*)shB;
  #pragma unroll
  for (int v = 0; v < 8; ++v){
    int item = v * 256 + tid;                      // 0..2047
    int slab = item >> 6, ln = item & 63;          // slab = ks*8 + ctl
    int ks = slab >> 3, ctl = slab & 7;
    shBv[item] = Bv[((ks * 32 + 8 * t + ctl) * 64) + ln];
  }

  const int w = tid >> 6, lane = tid & 63;
  const int m = lane & 15, qq = lane >> 4;
  const int node = nsorted[rowIdx + w * 16 + m];   // -1 = pad sentinel

  bf16x8 afrag[4];
  #pragma unroll
  for (int ks = 0; ks < 4; ++ks){
    bf16x8 f;
    if (node >= 0){
      const float4* src = (const float4*)(X + (size_t)node * 128 + ks * 32 + qq * 8);
      float4 a = src[0], b = src[1];
      f[0]=(short)f2bf(a.x); f[1]=(short)f2bf(a.y); f[2]=(short)f2bf(a.z); f[3]=(short)f2bf(a.w);
      f[4]=(short)f2bf(b.x); f[5]=(short)f2bf(b.y); f[6]=(short)f2bf(b.z); f[7]=(short)f2bf(b.w);
    } else {
      #pragma unroll
      for (int z = 0; z < 8; ++z) f[z] = 0;
    }
    afrag[ks] = f;
  }

  f32x4 acc[8];
  #pragma unroll
  for (int ct = 0; ct < 8; ++ct){
    acc[ct][0]=0.f; acc[ct][1]=0.f; acc[ct][2]=0.f; acc[ct][3]=0.f;
  }

  __syncthreads();
  #pragma unroll
  for (int ctl = 0; ctl < 8; ++ctl){
    #pragma unroll
    for (int ks = 0; ks < 4; ++ks){
      bf16x8 bf = shBv[(ks * 8 + ctl) * 64 + lane];
      acc[ctl] = __builtin_amdgcn_mfma_f32_16x16x32_bf16(afrag[ks], bf, acc[ctl], 0, 0, 0);
    }
  }

  const int col0 = lane & 15;
  #pragma unroll
  for (int rr = 0; rr < 4; ++rr){
    int row = nsorted[rowIdx + w * 16 + qq * 4 + rr];
    if (row < 0) continue;
    #pragma unroll
    for (int ctl = 0; ctl < 8; ++ctl)
      X0[(size_t)row * 128 + ctl * 16 + col0] = f2bf(acc[ctl][rr]);
  }
}

// ---------------------------------------------------------------------------
// seg_body v4: wide-load structure, on-the-fly logits.
// R4 FIX: ALL __shfl's in UNIFORM control flow.  v3 had
//   if (nr < m){ rn = __shfl(idx, nr); ... }
// with per-lane nr — ds_bpermute from a source lane whose own (nr<m) is
// false (EXEC=0) returns undefined data (e.g. m=17,g=2: requester sub=0
// wants lane 16, lane 16's own nr=17>=m -> inactive).  The prefetched row
// index was then garbage/zero and WAS used unmasked in a later group ->
// ~0.5 absmax on segments with chunk len>=17, varying with atomic order.
// Now: shfl executed by all 64 lanes (src clamped &63); only the FEAT LOAD
// is predicated on nr < m.  Lanes >= m hold idx=0 (safe dummy row id).
// ---------------------------------------------------------------------------
template<int OUT_BF16>
__device__ __forceinline__ void seg_body(const uint4* __restrict__ feat,
    const float* __restrict__ att, const int* __restrict__ rows_sorted,
    const int* __restrict__ offs, const int* __restrict__ cnt,
    const int* __restrict__ stype, void* __restrict__ outbuf,
    int S, int blockId, int tid){
  int wid = tid >> 6, lane = tid & 63;
  int s = blockId * 4 + wid;
  if (s >= S) return;
  int t = stype[s];
  int sub = lane >> 4, lane16 = lane & 15;         // sub-wave row slot, lane-in-row
  // att slice for this lane's 8 elements (head = lane16>>1 spans lane16 pairs)
  const float4* ap = (const float4*)(att + t * 128 + lane16 * 8);
  float4 A0 = ap[0], A1 = ap[1];
  int start = offs[s], len = cnt[s];
  float denom = 0.f;
  float acc[8];
  #pragma unroll
  for (int e = 0; e < 8; ++e) acc[e] = 0.f;

  for (int base = 0; base < len; base += 64){
    int m = len - base; if (m > 64) m = 64;
    int idx = 0;                                   // lanes >= m: safe dummy (row 0)
    if (lane < m) idx = rows_sorted[start + base + lane];
    int ng = (m + 3) >> 2;                         // groups of 4 rows
    uint4 uA = make_uint4(0,0,0,0), uB = make_uint4(0,0,0,0);
    {
      int r0 = __shfl(idx, sub);                   // uniform flow
      if (sub < m) uA = feat[(size_t)r0 * 16 + lane16];
      int r1 = __shfl(idx, 4 + sub);               // uniform flow
      if (4 + sub < m) uB = feat[(size_t)r1 * 16 + lane16];
    }
    for (int g = 0; g < ng; g += 2){
      {
        uint4 u = uA;
        int nr = (g + 2) * 4 + sub;
        int rn = __shfl(idx, nr & 63);             // UNCONDITIONAL (uniform)
        if (nr < m) uA = feat[(size_t)rn * 16 + lane16];  // load-only guard
        float x0 = bflo(u.x), x1 = bfhi(u.x), x2 = bflo(u.y), x3 = bfhi(u.y);
        float x4 = bflo(u.z), x5 = bfhi(u.z), x6 = bflo(u.w), x7 = bfhi(u.w);
        float p = x0*A0.x + x1*A0.y + x2*A0.z + x3*A0.w
                + x4*A1.x + x5*A1.y + x6*A1.z + x7*A1.w;
        p += __shfl_xor(p, 1);                     // complete 16-chan head dot
        float wgt = __expf(lrelu(p));
        wgt = (g * 4 + sub < m) ? wgt : 0.f;       // mask pad rows (exp(0)=1!)
        denom += wgt;
        acc[0] += wgt*x0; acc[1] += wgt*x1; acc[2] += wgt*x2; acc[3] += wgt*x3;
        acc[4] += wgt*x4; acc[5] += wgt*x5; acc[6] += wgt*x6; acc[7] += wgt*x7;
      }
      if (g + 1 < ng){                             // ng uniform -> uniform branch
        uint4 u = uB;
        int nr = (g + 3) * 4 + sub;
        int rn = __shfl(idx, nr & 63);             // UNCONDITIONAL (uniform)
        if (nr < m) uB = feat[(size_t)rn * 16 + lane16];
        float x0 = bflo(u.x), x1 = bfhi(u.x), x2 = bflo(u.y), x3 = bfhi(u.y);
        float x4 = bflo(u.z), x5 = bfhi(u.z), x6 = bflo(u.w), x7 = bfhi(u.w);
        float p = x0*A0.x + x1*A0.y + x2*A0.z + x3*A0.w
                + x4*A1.x + x5*A1.y + x6*A1.z + x7*A1.w;
        p += __shfl_xor(p, 1);
        float wgt = __expf(lrelu(p));
        wgt = ((g + 1) * 4 + sub < m) ? wgt : 0.f;
        denom += wgt;
        acc[0] += wgt*x0; acc[1] += wgt*x1; acc[2] += wgt*x2; acc[3] += wgt*x3;
        acc[4] += wgt*x4; acc[5] += wgt*x5; acc[6] += wgt*x6; acc[7] += wgt*x7;
      }
    }
  }
  // cross-sub-wave reduction (same lane16 <-> same head)
  denom += __shfl_xor(denom, 16);
  denom += __shfl_xor(denom, 32);
  #pragma unroll
  for (int e = 0; e < 8; ++e){
    acc[e] += __shfl_xor(acc[e], 16);
    acc[e] += __shfl_xor(acc[e], 32);
  }
  float inv = 1.f / (denom + 1e-16f);
  float v[8];
  #pragma unroll
  for (int e = 0; e < 8; ++e) v[e] = acc[e] * inv;

  if constexpr (OUT_BF16){
    if (sub == 0){
      uint4 pw;
      pw.x = (unsigned)f2bf(fmaxf(v[0],0.f)) | ((unsigned)f2bf(fmaxf(v[1],0.f)) << 16);
      pw.y = (unsigned)f2bf(fmaxf(v[2],0.f)) | ((unsigned)f2bf(fmaxf(v[3],0.f)) << 16);
      pw.z = (unsigned)f2bf(fmaxf(v[4],0.f)) | ((unsigned)f2bf(fmaxf(v[5],0.f)) << 16);
      pw.w = (unsigned)f2bf(fmaxf(v[6],0.f)) | ((unsigned)f2bf(fmaxf(v[7],0.f)) << 16);
      ((uint4*)outbuf)[(size_t)s * 16 + lane16] = pw;
    }
  } else {
    if (sub == 0){
      float4* op = (float4*)outbuf;
      op[(size_t)s * 32 + lane16 * 2]     = make_float4(v[0], v[1], v[2], v[3]);
      op[(size_t)s * 32 + lane16 * 2 + 1] = make_float4(v[4], v[5], v[6], v[7]);
    }
  }
}

// ---------------------------------------------------------------------------
// F_B: fused [place_v | seg1], MODULO-interleaved period 5.
// ---------------------------------------------------------------------------
__global__ __launch_bounds__(256) void k_place_seg1(
    const int* __restrict__ edges, const int* __restrict__ vertex, int NNZ,
    int* __restrict__ cursor, int* __restrict__ rows, int E,
    int nbPlace, int nbSeg,
    const uint4* __restrict__ X0, const float* __restrict__ att_e,
    const int* __restrict__ offs, const int* __restrict__ cnt,
    const int* __restrict__ etype, void* __restrict__ Xe){
  const int q = (int)blockIdx.x / 5, r = (int)blockIdx.x % 5;
  if (r == 0){
    if (q < nbPlace){
      int i = q * 256 + threadIdx.x;
      if (i < NNZ){
        int pos = atomicAdd(cursor + E + vertex[i], 1);
        rows[pos] = edges[i];
      }
    }
    return;
  }
  int segBlk = q * 4 + (r - 1);
  if (segBlk >= nbSeg) return;
  seg_body<1>(X0, att_e, rows, offs, cnt, etype, Xe, E, segBlk, threadIdx.x);
}

__global__ __launch_bounds__(256) void k_seg2(const uint4* __restrict__ Xe,
    const float* __restrict__ att_v, const int* __restrict__ rows,
    const int* __restrict__ offs, const int* __restrict__ cnt,
    const int* __restrict__ vtype, float* __restrict__ out, int N){
  seg_body<0>(Xe, att_v, rows, offs, cnt, vtype, out, N,
              (int)blockIdx.x, threadIdx.x);
}

extern "C" void kernel_launch(void* const* d_in, const int* in_sizes, int n_in,
                              void* d_out, int out_size, void* d_ws, size_t ws_size,
                              hipStream_t stream){
  const float* X      = (const float*)d_in[0];
  const float* W      = (const float*)d_in[1];
  const float* att_e  = (const float*)d_in[2];
  const float* att_v  = (const float*)d_in[3];
  const int*   vertex = (const int*)d_in[4];
  const int*   edges  = (const int*)d_in[5];
  const int*   vtype  = (const int*)d_in[6];
  const int*   etype  = (const int*)d_in[7];
  float* out = (float*)d_out;
  const int N   = in_sizes[0] / 128;
  const int NNZ = in_sizes[4];
  const int E   = in_sizes[7];
  const int S   = E + N;

  const int nbI = (NNZ + 255) / 256;                  // 3125 hist/place blocks
  const int nbHN = (N + 255) / 256;                   // 391 type-hist blocks
  const int nbS = (S + 1023) / 1024;
  const int nbSeg1 = (E + 3) / 4;                     // 12500 seg1 blocks
  const int nbPad = (N + 252 + 63) / 64;              // padded gemm blocks
  const int nsortedCap = nbPad * 64;                  // FULL gemm-grid coverage

  // workspace carve (identical to the 364us passing kernel: 47.1MB)
  char* wp = (char*)d_ws;
  int* cnt    = (int*)wp; wp += (size_t)S * 4;        // [0,E) edge, [E,S) vertex
  int* tcnt   = (int*)wp; wp += 16;                   // node-type counts
  int* tcur   = (int*)wp; wp += 16;                   // node-type cursors
  int* offs   = (int*)wp; wp += (size_t)S * 4;
  int* cursor = (int*)wp; wp += (size_t)S * 4;
  int* bsum   = (int*)wp; wp += 1024;                 // up to 256 block sums
  int* pbase  = (int*)wp; wp += 32;                   // padded bucket bases[5]
  int* rows   = (int*)wp; wp += (size_t)2 * NNZ * 4;  // [0,NNZ) edge-grp, [NNZ,2NNZ) vtx-grp
  int* nsorted= (int*)wp; wp += (size_t)nsortedCap * 4; // type-sorted node ids (pad = -1)
  unsigned short* X0 = (unsigned short*)wp; wp += (size_t)N * 128 * 2;
  unsigned short* Xe = (unsigned short*)wp; wp += (size_t)E * 128 * 2;
  short* Bfrag = (short*)wp; wp += (size_t)65536 * 2;

  hipMemsetAsync(cnt, 0, (size_t)(S + 8) * 4, stream);          // cnt + tcnt + tcur
  hipMemsetAsync(nsorted, 0xFF, (size_t)nsortedCap * 4, stream); // -1 sentinels

  k_histprep<<<nbI + nbHN + 256, 256, 0, stream>>>(edges, vertex, NNZ, cnt, E,
      nbI, vtype, N, tcnt, nbHN, W, Bfrag);

  k_scanA<<<nbS, 256, 0, stream>>>(cnt, S, bsum);
  k_scanB<<<1, 64, 0, stream>>>(bsum, nbS, tcnt, pbase);
  k_scanC<<<nbS + nbHN, 256, 0, stream>>>(cnt, S, bsum, offs, cursor,
      nbS, vtype, N, pbase, tcur, nsorted);

  // F_A interleaved: period 3 (1 gemm : 2 place_e); 2*nbPad >= nbI coverage
  k_gemm_place<<<3 * nbPad, 256, 0, stream>>>(X, Bfrag, nsorted, pbase,
      (unsigned short*)X0, edges, vertex, NNZ, cursor, rows, nbI);

  // F_B interleaved: period 5 (1 place_v : 4 seg1); 5*nbI = nbI + nbSeg1
  k_place_seg1<<<5 * nbI, 256, 0, stream>>>(edges, vertex, NNZ, cursor,
      rows, E, nbI, nbSeg1, (const uint4*)X0, att_e, offs, cnt, etype, Xe);

  // base rows pointer — offs[E..S) are global positions in [NNZ, 2NNZ)
  k_seg2<<<(N + 3) / 4, 256, 0, stream>>>((const uint4*)Xe, att_v,
      rows, offs + E, cnt + E, vtype, out, N);
}

// Round 5
// 316.636 us; speedup vs baseline: 1.1504x; 1.0944x over previous
//
#include <hip/hip_runtime.h>

typedef __attribute__((ext_vector_type(8))) short bf16x8;
typedef __attribute__((ext_vector_type(4))) float f32x4;

#define NEG_SLOPE 0.2f

__device__ __forceinline__ unsigned short f2bf(float f){
  unsigned u = __float_as_uint(f);
  u = (u + 0x7fffu + ((u >> 16) & 1u)) >> 16;   // RNE
  return (unsigned short)u;
}
__device__ __forceinline__ float bflo(unsigned u){ return __uint_as_float(u << 16); }
__device__ __forceinline__ float bfhi(unsigned u){ return __uint_as_float(u & 0xffff0000u); }
__device__ __forceinline__ float lrelu(float x){ return x > 0.f ? x : NEG_SLOPE * x; }

// ---------------------------------------------------------------------------
// K0: [typehist | bprep].  Edge/vertex hist moved to K_A (overlaps gemm).
// ---------------------------------------------------------------------------
__global__ __launch_bounds__(256) void k_prep(
    const int* __restrict__ vtype, int N, int* __restrict__ tcnt, int nbHN,
    const float* __restrict__ W, short* __restrict__ Bfrag){
  __shared__ int lcnt[4];
  int b = (int)blockIdx.x;
  if (b < nbHN){
    if (threadIdx.x < 4) lcnt[threadIdx.x] = 0;
    __syncthreads();
    int i = b * 256 + threadIdx.x;
    if (i < N) atomicAdd(&lcnt[vtype[i]], 1);
    __syncthreads();
    if (threadIdx.x < 4 && lcnt[threadIdx.x] > 0)
      atomicAdd(tcnt + threadIdx.x, lcnt[threadIdx.x]);
    return;
  }
  b -= nbHN;
  int u = b * 256 + threadIdx.x;                   // 0..65535
  int j = u & 7, lane = (u >> 3) & 63, ct = (u >> 9) & 31, ks = u >> 14;
  int k = ks * 32 + ((lane >> 4) << 3) + j;
  int col = (ct << 4) + (lane & 15);
  int t = col >> 7, o = col & 127;
  Bfrag[u] = (short)f2bf(W[(t * 128 + k) * 128 + o]);
}

// padded type-bucket bases from tcnt (1 block)
__global__ void k_pbase(const int* __restrict__ tcnt, int* __restrict__ pbase){
  if (threadIdx.x == 0 && blockIdx.x == 0){
    int pb = 0;
    for (int t = 0; t < 4; ++t){
      pbase[t] = pb;
      pb += ((tcnt[t] + 63) >> 6) << 6;            // pad to 64-row multiple
    }
    pbase[4] = pb;
  }
}

// node placement (type-sorted nsorted), standalone so gemm can start early.
// tcur atomics: only ~1.5k RMWs total — negligible vs the 25G/s ceiling.
__global__ __launch_bounds__(256) void k_nodeplace(
    const int* __restrict__ vtype, int N, const int* __restrict__ pbase,
    int* __restrict__ tcur, int* __restrict__ nsorted){
  __shared__ int lcnt[4];
  __shared__ int gbase[4];
  int t = threadIdx.x;
  if (t < 4) lcnt[t] = 0;
  __syncthreads();
  int i = (int)blockIdx.x * 256 + t;
  int tt = 0, rank = 0;
  bool valid = i < N;
  if (valid){ tt = vtype[i]; rank = atomicAdd(&lcnt[tt], 1); }
  __syncthreads();
  if (t < 4 && lcnt[t] > 0) gbase[t] = atomicAdd(tcur + t, lcnt[t]);
  __syncthreads();
  if (valid) nsorted[pbase[tt] + gbase[tt] + rank] = i;
}

// ---------------------------------------------------------------------------
// K_A: [gemm | hist+ranks], MODULO-interleaved period 3 (r0 gemm, r1/r2 hist).
// The hist role's 1.6M atomics hit the device atomic-throughput ceiling
// (~25G/s -> 64us) but consume no VALU/MFMA/HBM — gemm blocks fill the CUs
// meanwhile.  atomicAdd's RETURN is each incidence's within-key rank; storing
// it makes placement a pure scatter (halves total atomic count).
// gemm role is verbatim the proven R4 code.
// ---------------------------------------------------------------------------
__global__ __launch_bounds__(256, 3) void k_gemm_hist(const float* __restrict__ X,
    const short* __restrict__ Bfrag, const int* __restrict__ nsorted,
    const int* __restrict__ pbase, unsigned short* __restrict__ X0,
    const int* __restrict__ edges, const int* __restrict__ vertex, int NNZ,
    int* __restrict__ cnt, int E,
    int* __restrict__ rank_e, int* __restrict__ rank_v, int nbHist){
  __shared__ short shB[8 * 4 * 64 * 8];            // 32KB: type slab, frag order
  const int tid = threadIdx.x;
  const int q = (int)blockIdx.x / 3, r = (int)blockIdx.x % 3;

  if (r != 0){                                     // hist role
    int hb = 2 * q + (r - 1);
    if (hb < nbHist){
      int i = hb * 256 + tid;
      if (i < NNZ){
        rank_e[i] = atomicAdd(cnt + edges[i], 1);
        rank_v[i] = atomicAdd(cnt + E + vertex[i], 1);
      }
    }
    return;
  }

  const int rowIdx = q * 64;
  const int t = (rowIdx >= pbase[1]) + (rowIdx >= pbase[2]) + (rowIdx >= pbase[3]);

  // stage this type's full B (8 ct x 4 ks x 64 lanes, bf16x8 units)
  const bf16x8* Bv = (const bf16x8*)Bfrag;
  bf16x8* shBv = (bf16x8*)shB;
  #pragma unroll
  for (int v = 0; v < 8; ++v){
    int item = v * 256 + tid;                      // 0..2047
    int slab = item >> 6, ln = item & 63;          // slab = ks*8 + ctl
    int ks = slab >> 3, ctl = slab & 7;
    shBv[item] = Bv[((ks * 32 + 8 * t + ctl) * 64) + ln];
  }

  const int w = tid >> 6, lane = tid & 63;
  const int m = lane & 15, qq = lane >> 4;
  const int node = nsorted[rowIdx + w * 16 + m];   // -1 = pad sentinel

  bf16x8 afrag[4];
  #pragma unroll
  for (int ks = 0; ks < 4; ++ks){
    bf16x8 f;
    if (node >= 0){
      const float4* src = (const float4*)(X + (size_t)node * 128 + ks * 32 + qq * 8);
      float4 a = src[0], b = src[1];
      f[0]=(short)f2bf(a.x); f[1]=(short)f2bf(a.y); f[2]=(short)f2bf(a.z); f[3]=(short)f2bf(a.w);
      f[4]=(short)f2bf(b.x); f[5]=(short)f2bf(b.y); f[6]=(short)f2bf(b.z); f[7]=(short)f2bf(b.w);
    } else {
      #pragma unroll
      for (int z = 0; z < 8; ++z) f[z] = 0;
    }
    afrag[ks] = f;
  }

  f32x4 acc[8];
  #pragma unroll
  for (int ct = 0; ct < 8; ++ct){
    acc[ct][0]=0.f; acc[ct][1]=0.f; acc[ct][2]=0.f; acc[ct][3]=0.f;
  }

  __syncthreads();
  #pragma unroll
  for (int ctl = 0; ctl < 8; ++ctl){
    #pragma unroll
    for (int ks = 0; ks < 4; ++ks){
      bf16x8 bf = shBv[(ks * 8 + ctl) * 64 + lane];
      acc[ctl] = __builtin_amdgcn_mfma_f32_16x16x32_bf16(afrag[ks], bf, acc[ctl], 0, 0, 0);
    }
  }

  const int col0 = lane & 15;
  #pragma unroll
  for (int rr = 0; rr < 4; ++rr){
    int row = nsorted[rowIdx + w * 16 + qq * 4 + rr];
    if (row < 0) continue;
    #pragma unroll
    for (int ctl = 0; ctl < 8; ++ctl)
      X0[(size_t)row * 128 + ctl * 16 + col0] = f2bf(acc[ctl][rr]);
  }
}

// ---------------------------------------------------------------------------
// scans: block sums -> serial block-offset scan -> offs (no cursor needed).
// ---------------------------------------------------------------------------
__global__ __launch_bounds__(256) void k_scanA(const int* __restrict__ cnt, int S,
                                               int* __restrict__ bsum){
  __shared__ int sh[256];
  int base = blockIdx.x * 1024 + threadIdx.x * 4;
  int s = 0;
  #pragma unroll
  for (int k = 0; k < 4; ++k){ int idx = base + k; if (idx < S) s += cnt[idx]; }
  sh[threadIdx.x] = s; __syncthreads();
  for (int off = 128; off > 0; off >>= 1){
    if (threadIdx.x < off) sh[threadIdx.x] += sh[threadIdx.x + off];
    __syncthreads();
  }
  if (threadIdx.x == 0) bsum[blockIdx.x] = sh[0];
}

__global__ void k_scanB2(int* bsum, int nb){
  if (threadIdx.x == 0 && blockIdx.x == 0){
    int run = 0;
    for (int b = 0; b < nb; ++b){ int v = bsum[b]; bsum[b] = run; run += v; }
  }
}

__global__ __launch_bounds__(256) void k_scanC2(const int* __restrict__ cnt, int S,
    const int* __restrict__ bsum, int* __restrict__ offs){
  __shared__ int sh[256];
  int t = threadIdx.x;
  int b = (int)blockIdx.x;
  int base = b * 1024 + t * 4;
  int c[4]; int s = 0;
  #pragma unroll
  for (int k = 0; k < 4; ++k){ int idx = base + k; c[k] = (idx < S) ? cnt[idx] : 0; s += c[k]; }
  sh[t] = s; __syncthreads();
  for (int off = 1; off < 256; off <<= 1){
    int v = (t >= off) ? sh[t - off] : 0; __syncthreads();
    sh[t] += v; __syncthreads();
  }
  int run = bsum[b] + sh[t] - s;                   // exclusive prefix for this thread
  #pragma unroll
  for (int k = 0; k < 4; ++k){
    int idx = base + k;
    if (idx < S){ offs[idx] = run; run += c[k]; }
  }
}

// ---------------------------------------------------------------------------
// K_B: [place_e | place_v] — PURE SCATTER (ranks precomputed in K_A's hist),
// zero atomics.  period 2.
// ---------------------------------------------------------------------------
__global__ __launch_bounds__(256) void k_place(
    const int* __restrict__ edges, const int* __restrict__ vertex, int NNZ,
    const int* __restrict__ offs, const int* __restrict__ rank_e,
    const int* __restrict__ rank_v, int* __restrict__ rows, int E){
  int q = (int)blockIdx.x >> 1, r = (int)blockIdx.x & 1;
  int i = q * 256 + (int)threadIdx.x;
  if (i >= NNZ) return;
  if (r == 0) rows[offs[edges[i]]      + rank_e[i]] = vertex[i];
  else        rows[offs[E + vertex[i]] + rank_v[i]] = edges[i];
}

// ---------------------------------------------------------------------------
// seg_body v4 (UNCHANGED from the passing R4 kernel — all shfl uniform).
// ---------------------------------------------------------------------------
template<int OUT_BF16>
__device__ __forceinline__ void seg_body(const uint4* __restrict__ feat,
    const float* __restrict__ att, const int* __restrict__ rows_sorted,
    const int* __restrict__ offs, const int* __restrict__ cnt,
    const int* __restrict__ stype, void* __restrict__ outbuf,
    int S, int blockId, int tid){
  int wid = tid >> 6, lane = tid & 63;
  int s = blockId * 4 + wid;
  if (s >= S) return;
  int t = stype[s];
  int sub = lane >> 4, lane16 = lane & 15;         // sub-wave row slot, lane-in-row
  const float4* ap = (const float4*)(att + t * 128 + lane16 * 8);
  float4 A0 = ap[0], A1 = ap[1];
  int start = offs[s], len = cnt[s];
  float denom = 0.f;
  float acc[8];
  #pragma unroll
  for (int e = 0; e < 8; ++e) acc[e] = 0.f;

  for (int base = 0; base < len; base += 64){
    int m = len - base; if (m > 64) m = 64;
    int idx = 0;                                   // lanes >= m: safe dummy (row 0)
    if (lane < m) idx = rows_sorted[start + base + lane];
    int ng = (m + 3) >> 2;                         // groups of 4 rows
    uint4 uA = make_uint4(0,0,0,0), uB = make_uint4(0,0,0,0);
    {
      int r0 = __shfl(idx, sub);                   // uniform flow
      if (sub < m) uA = feat[(size_t)r0 * 16 + lane16];
      int r1 = __shfl(idx, 4 + sub);               // uniform flow
      if (4 + sub < m) uB = feat[(size_t)r1 * 16 + lane16];
    }
    for (int g = 0; g < ng; g += 2){
      {
        uint4 u = uA;
        int nr = (g + 2) * 4 + sub;
        int rn = __shfl(idx, nr & 63);             // UNCONDITIONAL (uniform)
        if (nr < m) uA = feat[(size_t)rn * 16 + lane16];  // load-only guard
        float x0 = bflo(u.x), x1 = bfhi(u.x), x2 = bflo(u.y), x3 = bfhi(u.y);
        float x4 = bflo(u.z), x5 = bfhi(u.z), x6 = bflo(u.w), x7 = bfhi(u.w);
        float p = x0*A0.x + x1*A0.y + x2*A0.z + x3*A0.w
                + x4*A1.x + x5*A1.y + x6*A1.z + x7*A1.w;
        p += __shfl_xor(p, 1);                     // complete 16-chan head dot
        float wgt = __expf(lrelu(p));
        wgt = (g * 4 + sub < m) ? wgt : 0.f;       // mask pad rows (exp(0)=1!)
        denom += wgt;
        acc[0] += wgt*x0; acc[1] += wgt*x1; acc[2] += wgt*x2; acc[3] += wgt*x3;
        acc[4] += wgt*x4; acc[5] += wgt*x5; acc[6] += wgt*x6; acc[7] += wgt*x7;
      }
      if (g + 1 < ng){                             // ng uniform -> uniform branch
        uint4 u = uB;
        int nr = (g + 3) * 4 + sub;
        int rn = __shfl(idx, nr & 63);             // UNCONDITIONAL (uniform)
        if (nr < m) uB = feat[(size_t)rn * 16 + lane16];
        float x0 = bflo(u.x), x1 = bfhi(u.x), x2 = bflo(u.y), x3 = bfhi(u.y);
        float x4 = bflo(u.z), x5 = bfhi(u.z), x6 = bflo(u.w), x7 = bfhi(u.w);
        float p = x0*A0.x + x1*A0.y + x2*A0.z + x3*A0.w
                + x4*A1.x + x5*A1.y + x6*A1.z + x7*A1.w;
        p += __shfl_xor(p, 1);
        float wgt = __expf(lrelu(p));
        wgt = ((g + 1) * 4 + sub < m) ? wgt : 0.f;
        denom += wgt;
        acc[0] += wgt*x0; acc[1] += wgt*x1; acc[2] += wgt*x2; acc[3] += wgt*x3;
        acc[4] += wgt*x4; acc[5] += wgt*x5; acc[6] += wgt*x6; acc[7] += wgt*x7;
      }
    }
  }
  // cross-sub-wave reduction (same lane16 <-> same head)
  denom += __shfl_xor(denom, 16);
  denom += __shfl_xor(denom, 32);
  #pragma unroll
  for (int e = 0; e < 8; ++e){
    acc[e] += __shfl_xor(acc[e], 16);
    acc[e] += __shfl_xor(acc[e], 32);
  }
  float inv = 1.f / (denom + 1e-16f);
  float v[8];
  #pragma unroll
  for (int e = 0; e < 8; ++e) v[e] = acc[e] * inv;

  if constexpr (OUT_BF16){
    if (sub == 0){
      uint4 pw;
      pw.x = (unsigned)f2bf(fmaxf(v[0],0.f)) | ((unsigned)f2bf(fmaxf(v[1],0.f)) << 16);
      pw.y = (unsigned)f2bf(fmaxf(v[2],0.f)) | ((unsigned)f2bf(fmaxf(v[3],0.f)) << 16);
      pw.z = (unsigned)f2bf(fmaxf(v[4],0.f)) | ((unsigned)f2bf(fmaxf(v[5],0.f)) << 16);
      pw.w = (unsigned)f2bf(fmaxf(v[6],0.f)) | ((unsigned)f2bf(fmaxf(v[7],0.f)) << 16);
      ((uint4*)outbuf)[(size_t)s * 16 + lane16] = pw;
    }
  } else {
    if (sub == 0){
      float4* op = (float4*)outbuf;
      op[(size_t)s * 32 + lane16 * 2]     = make_float4(v[0], v[1], v[2], v[3]);
      op[(size_t)s * 32 + lane16 * 2 + 1] = make_float4(v[4], v[5], v[6], v[7]);
    }
  }
}

__global__ __launch_bounds__(256) void k_seg1(const uint4* __restrict__ X0,
    const float* __restrict__ att_e, const int* __restrict__ rows,
    const int* __restrict__ offs, const int* __restrict__ cnt,
    const int* __restrict__ etype, void* __restrict__ Xe, int E){
  seg_body<1>(X0, att_e, rows, offs, cnt, etype, Xe, E,
              (int)blockIdx.x, threadIdx.x);
}

__global__ __launch_bounds__(256) void k_seg2(const uint4* __restrict__ Xe,
    const float* __restrict__ att_v, const int* __restrict__ rows,
    const int* __restrict__ offs, const int* __restrict__ cnt,
    const int* __restrict__ vtype, float* __restrict__ out, int N){
  seg_body<0>(Xe, att_v, rows, offs, cnt, vtype, out, N,
              (int)blockIdx.x, threadIdx.x);
}

extern "C" void kernel_launch(void* const* d_in, const int* in_sizes, int n_in,
                              void* d_out, int out_size, void* d_ws, size_t ws_size,
                              hipStream_t stream){
  const float* X      = (const float*)d_in[0];
  const float* W      = (const float*)d_in[1];
  const float* att_e  = (const float*)d_in[2];
  const float* att_v  = (const float*)d_in[3];
  const int*   vertex = (const int*)d_in[4];
  const int*   edges  = (const int*)d_in[5];
  const int*   vtype  = (const int*)d_in[6];
  const int*   etype  = (const int*)d_in[7];
  float* out = (float*)d_out;
  const int N   = in_sizes[0] / 128;
  const int NNZ = in_sizes[4];
  const int E   = in_sizes[7];
  const int S   = E + N;

  const int nbI = (NNZ + 255) / 256;                  // 3125 hist blocks
  const int nbHN = (N + 255) / 256;                   // 391 type-hist blocks
  const int nbS = (S + 1023) / 1024;
  const int nbSeg1 = (E + 3) / 4;                     // 12500 seg1 blocks
  const int nbPad = (N + 252 + 63) / 64;              // padded gemm blocks
  const int nsortedCap = nbPad * 64;                  // FULL gemm-grid coverage

  // workspace carve (~52.9MB: dropped cursor, added rank_e/rank_v)
  char* wp = (char*)d_ws;
  int* cnt    = (int*)wp; wp += (size_t)S * 4;        // [0,E) edge, [E,S) vertex
  int* tcnt   = (int*)wp; wp += 16;                   // node-type counts
  int* tcur   = (int*)wp; wp += 16;                   // node-type cursors
  int* offs   = (int*)wp; wp += (size_t)S * 4;
  int* bsum   = (int*)wp; wp += 1024;                 // up to 256 block sums
  int* pbase  = (int*)wp; wp += 32;                   // padded bucket bases[5]
  int* rows   = (int*)wp; wp += (size_t)2 * NNZ * 4;  // [0,NNZ) edge-grp, [NNZ,2NNZ) vtx-grp
  int* nsorted= (int*)wp; wp += (size_t)nsortedCap * 4; // type-sorted node ids (pad = -1)
  int* rank_e = (int*)wp; wp += (size_t)NNZ * 4;      // within-edge-key arrival rank
  int* rank_v = (int*)wp; wp += (size_t)NNZ * 4;      // within-vtx-key arrival rank
  unsigned short* X0 = (unsigned short*)wp; wp += (size_t)N * 128 * 2;
  unsigned short* Xe = (unsigned short*)wp; wp += (size_t)E * 128 * 2;
  short* Bfrag = (short*)wp; wp += (size_t)65536 * 2;

  hipMemsetAsync(cnt, 0, (size_t)(S + 8) * 4, stream);          // cnt + tcnt + tcur
  hipMemsetAsync(nsorted, 0xFF, (size_t)nsortedCap * 4, stream); // -1 sentinels

  // prep: type-hist + Bfrag pack (fast; no incidence atomics here any more)
  k_prep<<<nbHN + 256, 256, 0, stream>>>(vtype, N, tcnt, nbHN, W, Bfrag);
  k_pbase<<<1, 64, 0, stream>>>(tcnt, pbase);
  k_nodeplace<<<nbHN, 256, 0, stream>>>(vtype, N, pbase, tcur, nsorted);

  // K_A: gemm overlapped with the atomic-ceiling-bound hist (period 3).
  k_gemm_hist<<<3 * nbPad, 256, 0, stream>>>(X, Bfrag, nsorted, pbase,
      (unsigned short*)X0, edges, vertex, NNZ, cnt, E, rank_e, rank_v, nbI);

  k_scanA<<<nbS, 256, 0, stream>>>(cnt, S, bsum);
  k_scanB2<<<1, 64, 0, stream>>>(bsum, nbS);
  k_scanC2<<<nbS, 256, 0, stream>>>(cnt, S, bsum, offs);

  // K_B: atomic-free CSR placement (both groupings), period 2
  k_place<<<2 * nbI, 256, 0, stream>>>(edges, vertex, NNZ, offs,
      rank_e, rank_v, rows, E);

  k_seg1<<<nbSeg1, 256, 0, stream>>>((const uint4*)X0, att_e, rows,
      offs, cnt, etype, Xe, E);

  // base rows pointer — offs[E..S) are global positions in [NNZ, 2NNZ)
  k_seg2<<<(N + 3) / 4, 256, 0, stream>>>((const uint4*)Xe, att_v,
      rows, offs + E, cnt + E, vtype, out, N);
}